// Round 1
// baseline (546.465 us; speedup 1.0000x reference)
//
#include <hip/hip_runtime.h>

#define N_NODES 100000
#define N_EDGES 3200000

// Workspace layout (as 4-byte words):
//   [0,      N)    deg   (int)   in-degree count (excl. self loop)
//   [N,     2N)    dinv  (float) 1/sqrt(deg+1)
//   [2N,    3N)    xs    (float) x[i]*dinv[i]
//   [3N,    4N)    s     (float) scatter accumulator layer 1
//   [4N,    5N)    us    (float) u[i]*dinv[i]
//   [5N,    6N)    uself (float) u[i]/deg_tot[i]
//   [6N,    7N)    r     (float) scatter accumulator layer 2
//   [7N, 7N+17)    vc    (float) v[0..15]=W2@Wl, vc[16]=b2@Wl+bl

__global__ void gcn_prep(const float* __restrict__ W2, const float* __restrict__ b2,
                         const float* __restrict__ Wl, const float* __restrict__ bl,
                         float* __restrict__ vc) {
    int t = threadIdx.x;
    if (t < 16) {
        float acc = 0.f;
        #pragma unroll
        for (int k = 0; k < 16; ++k) acc += W2[t * 16 + k] * Wl[k];
        vc[t] = acc;
    } else if (t == 16) {
        float acc = bl[0];
        #pragma unroll
        for (int k = 0; k < 16; ++k) acc += b2[k] * Wl[k];
        vc[16] = acc;
    }
}

__global__ void gcn_deg(const int* __restrict__ dst, int* __restrict__ deg) {
    int e = blockIdx.x * blockDim.x + threadIdx.x;
    if (e < N_EDGES) atomicAdd(&deg[dst[e]], 1);
}

__global__ void gcn_node1(const float* __restrict__ x, const int* __restrict__ deg,
                          float* __restrict__ dinv, float* __restrict__ xs) {
    int i = blockIdx.x * blockDim.x + threadIdx.x;
    if (i < N_NODES) {
        float d = (float)(deg[i] + 1);          // + self loop
        float di = 1.0f / sqrtf(d);
        dinv[i] = di;
        xs[i] = x[i] * di;
    }
}

__global__ void gcn_scatter(const int* __restrict__ src, const int* __restrict__ dst,
                            const float* __restrict__ val, float* __restrict__ acc) {
    int e = blockIdx.x * blockDim.x + threadIdx.x;
    if (e < N_EDGES) atomicAdd(&acc[dst[e]], val[src[e]]);
}

__global__ void gcn_node2(const float* __restrict__ x, const float* __restrict__ s,
                          const float* __restrict__ dinv,
                          const float* __restrict__ W1, const float* __restrict__ b1,
                          const float* __restrict__ vc,
                          float* __restrict__ us, float* __restrict__ uself) {
    int i = blockIdx.x * blockDim.x + threadIdx.x;
    if (i < N_NODES) {
        float di = dinv[i];
        float s1 = di * s[i] + x[i] * di * di;   // layer-1 aggregated scalar
        float u = 0.f;
        #pragma unroll
        for (int c = 0; c < 16; ++c) {
            float h = fmaxf(W1[c] * s1 + b1[c], 0.f);   // relu(h1[i,c])
            u += h * vc[c];                              // · (W2@Wl)[c]
        }
        us[i]    = u * di;
        uself[i] = u * di * di;
    }
}

__global__ void gcn_out(const float* __restrict__ r, const float* __restrict__ dinv,
                        const float* __restrict__ uself, const float* __restrict__ vc,
                        float* __restrict__ out) {
    int i = blockIdx.x * blockDim.x + threadIdx.x;
    if (i < N_NODES) {
        out[i] = dinv[i] * r[i] + uself[i] + vc[16];
    }
}

extern "C" void kernel_launch(void* const* d_in, const int* in_sizes, int n_in,
                              void* d_out, int out_size, void* d_ws, size_t ws_size,
                              hipStream_t stream) {
    const float* x   = (const float*)d_in[0];
    const int*   ei  = (const int*)d_in[1];   // [2, E] row-major: src then dst
    const float* W1  = (const float*)d_in[2];
    const float* b1  = (const float*)d_in[3];
    const float* W2  = (const float*)d_in[4];
    const float* b2  = (const float*)d_in[5];
    const float* Wl  = (const float*)d_in[6];
    const float* bl  = (const float*)d_in[7];
    float* out = (float*)d_out;

    const int* src = ei;
    const int* dst = ei + N_EDGES;

    const size_t N = N_NODES;
    int*   deg   = (int*)d_ws;
    float* dinv  = (float*)d_ws + N;
    float* xs    = (float*)d_ws + 2 * N;
    float* s     = (float*)d_ws + 3 * N;
    float* us    = (float*)d_ws + 4 * N;
    float* uself = (float*)d_ws + 5 * N;
    float* r     = (float*)d_ws + 6 * N;
    float* vc    = (float*)d_ws + 7 * N;

    // zero deg, s, r (and everything in between — 2.8 MB, sub-µs)
    hipMemsetAsync(d_ws, 0, 7 * N * sizeof(float), stream);

    const int TB = 256;
    const int edge_blocks = (N_EDGES + TB - 1) / TB;
    const int node_blocks = (N_NODES + TB - 1) / TB;

    gcn_prep<<<1, 64, 0, stream>>>(W2, b2, Wl, bl, vc);
    gcn_deg<<<edge_blocks, TB, 0, stream>>>(dst, deg);
    gcn_node1<<<node_blocks, TB, 0, stream>>>(x, deg, dinv, xs);
    gcn_scatter<<<edge_blocks, TB, 0, stream>>>(src, dst, xs, s);
    gcn_node2<<<node_blocks, TB, 0, stream>>>(x, s, dinv, W1, b1, vc, us, uself);
    gcn_scatter<<<edge_blocks, TB, 0, stream>>>(src, dst, us, r);
    gcn_out<<<node_blocks, TB, 0, stream>>>(r, dinv, uself, vc, out);
}

// Round 2
// 219.766 us; speedup vs baseline: 2.4866x; 2.4866x over previous
//
#include <hip/hip_runtime.h>

#define N_NODES 100000
#define N_EDGES 3200000
#define BSHIFT  14
#define BSIZE   16384          // nodes per bucket (64 KB fp32 in LDS)
#define NBUCK   7              // 7*16384 = 114688 >= 100000
#define ACC_SUB 32             // partial-accumulator blocks per bucket
#define ACC_T   512
#define P2_T    256
#define P2_TILE 2048

// ws layout (4-byte words):
//  [0..8)    bucketCnt   [8..16) bucketBase  [16..24) bucketCursor  [24..41) vc
//  [64 .. 64+E)                         pedge   (u32 packed: src | dst_local<<17)
//  [64+E .. +NBUCK*ACC_SUB*BSIZE)       partials (float)
//  then dinv[N], xs[N], us[N], uself[N]

__global__ void p1_count(const int* __restrict__ dst, unsigned* __restrict__ cnt) {
    __shared__ unsigned lc[8];
    if (threadIdx.x < 8) lc[threadIdx.x] = 0;
    __syncthreads();
    int stride = gridDim.x * blockDim.x;
    for (int e = blockIdx.x * blockDim.x + threadIdx.x; e < N_EDGES; e += stride)
        atomicAdd(&lc[((unsigned)dst[e]) >> BSHIFT], 1u);
    __syncthreads();
    if (threadIdx.x < 8) atomicAdd(&cnt[threadIdx.x], lc[threadIdx.x]);
}

__global__ void scan_prep(const unsigned* __restrict__ cnt, unsigned* __restrict__ base,
                          unsigned* __restrict__ cursor, float* __restrict__ vc,
                          const float* __restrict__ W2, const float* __restrict__ b2,
                          const float* __restrict__ Wl, const float* __restrict__ bl) {
    int t = threadIdx.x;
    if (t == 0) {
        unsigned run = 0;
        for (int b = 0; b < NBUCK; ++b) { base[b] = run; cursor[b] = run; run += cnt[b]; }
        base[NBUCK] = run;
    }
    if (t < 16) {
        float a = 0.f;
        #pragma unroll
        for (int k = 0; k < 16; ++k) a += W2[t * 16 + k] * Wl[k];
        vc[t] = a;
    } else if (t == 16) {
        float a = bl[0];
        #pragma unroll
        for (int k = 0; k < 16; ++k) a += b2[k] * Wl[k];
        vc[16] = a;
    }
}

__global__ __launch_bounds__(P2_T) void p2_partition(const int* __restrict__ src,
                                                     const int* __restrict__ dst,
                                                     unsigned* __restrict__ cursor,
                                                     unsigned* __restrict__ pedge) {
    __shared__ unsigned cnt[8], loff[8], gbase[8];
    __shared__ unsigned stage[P2_TILE];
    int tid = threadIdx.x;
    unsigned tb = blockIdx.x * P2_TILE;

    unsigned sv[8], dv[8], loc[8];
    int bk[8];
    if (tid < 8) cnt[tid] = 0;
    __syncthreads();
    #pragma unroll
    for (int k = 0; k < 8; ++k) {
        unsigned e = tb + k * P2_T + tid;
        if (e < N_EDGES) { sv[k] = (unsigned)src[e]; dv[k] = (unsigned)dst[e]; }
        else             { sv[k] = 0; dv[k] = 0xFFFFFFFFu; }
    }
    #pragma unroll
    for (int k = 0; k < 8; ++k) {
        if (dv[k] != 0xFFFFFFFFu) {
            bk[k] = dv[k] >> BSHIFT;
            loc[k] = atomicAdd(&cnt[bk[k]], 1u);
        }
    }
    __syncthreads();
    if (tid == 0) {
        unsigned run = 0;
        for (int b = 0; b < NBUCK; ++b) { loff[b] = run; run += cnt[b]; }
        loff[7] = run;
    }
    __syncthreads();
    if (tid < NBUCK) gbase[tid] = atomicAdd(&cursor[tid], cnt[tid]);
    // stage packed edges grouped by bucket
    #pragma unroll
    for (int k = 0; k < 8; ++k)
        if (dv[k] != 0xFFFFFFFFu)
            stage[loff[bk[k]] + loc[k]] = sv[k] | ((dv[k] & (BSIZE - 1)) << 17);
    __syncthreads();
    unsigned total = loff[7];
    for (unsigned j = tid; j < total; j += P2_T) {
        int b = 0;
        while (b < NBUCK - 1 && j >= loff[b + 1]) ++b;
        pedge[gbase[b] + (j - loff[b])] = stage[j];
    }
}

__global__ __launch_bounds__(ACC_T) void acc_kernel(const unsigned* __restrict__ pedge,
                                                    const unsigned* __restrict__ base,
                                                    const unsigned* __restrict__ cnt,
                                                    const float* __restrict__ vals,
                                                    float* __restrict__ partials) {
    __shared__ float lacc[BSIZE];
    int bu = blockIdx.x >> 5, sub = blockIdx.x & 31;
    for (int i = threadIdx.x; i < BSIZE; i += ACC_T) lacc[i] = 0.f;
    __syncthreads();
    unsigned beg = base[bu], n = cnt[bu];
    unsigned tib = (unsigned)sub * ACC_T + threadIdx.x;   // 0..16383
    for (unsigned j = tib; j < n; j += ACC_SUB * ACC_T) {
        unsigned w = pedge[beg + j];
        float v = vals ? vals[w & 0x1FFFFu] : 1.0f;
        atomicAdd(&lacc[w >> 17], v);
    }
    __syncthreads();
    float* out = partials + (((unsigned)blockIdx.x) << BSHIFT);
    for (int i = threadIdx.x; i < BSIZE; i += ACC_T) out[i] = lacc[i];
}

__global__ void red_deg(const float* __restrict__ partials, const float* __restrict__ x,
                        float* __restrict__ dinv, float* __restrict__ xs) {
    int i = blockIdx.x * blockDim.x + threadIdx.x;
    if (i >= N_NODES) return;
    int b = i >> BSHIFT, l = i & (BSIZE - 1);
    const float* p = partials + ((unsigned)(b * ACC_SUB) << BSHIFT) + l;
    float s = 1.0f;  // + self loop
    #pragma unroll
    for (int k = 0; k < ACC_SUB; ++k) s += p[(unsigned)k << BSHIFT];
    float di = rsqrtf(s);
    dinv[i] = di;
    xs[i] = x[i] * di;
}

__global__ void red_s(const float* __restrict__ partials, const float* __restrict__ x,
                      const float* __restrict__ dinv,
                      const float* __restrict__ W1, const float* __restrict__ b1,
                      const float* __restrict__ vc,
                      float* __restrict__ us, float* __restrict__ uself) {
    int i = blockIdx.x * blockDim.x + threadIdx.x;
    if (i >= N_NODES) return;
    int b = i >> BSHIFT, l = i & (BSIZE - 1);
    const float* p = partials + ((unsigned)(b * ACC_SUB) << BSHIFT) + l;
    float sum = 0.f;
    #pragma unroll
    for (int k = 0; k < ACC_SUB; ++k) sum += p[(unsigned)k << BSHIFT];
    float di = dinv[i];
    float s1 = di * sum + x[i] * di * di;    // layer-1 aggregated scalar
    float u = 0.f;
    #pragma unroll
    for (int c = 0; c < 16; ++c) {
        float h = fmaxf(W1[c] * s1 + b1[c], 0.f);
        u += h * vc[c];
    }
    us[i] = u * di;
    uself[i] = u * di * di;
}

__global__ void red_r(const float* __restrict__ partials, const float* __restrict__ dinv,
                      const float* __restrict__ uself, const float* __restrict__ vc,
                      float* __restrict__ out) {
    int i = blockIdx.x * blockDim.x + threadIdx.x;
    if (i >= N_NODES) return;
    int b = i >> BSHIFT, l = i & (BSIZE - 1);
    const float* p = partials + ((unsigned)(b * ACC_SUB) << BSHIFT) + l;
    float sum = 0.f;
    #pragma unroll
    for (int k = 0; k < ACC_SUB; ++k) sum += p[(unsigned)k << BSHIFT];
    out[i] = dinv[i] * sum + uself[i] + vc[16];
}

extern "C" void kernel_launch(void* const* d_in, const int* in_sizes, int n_in,
                              void* d_out, int out_size, void* d_ws, size_t ws_size,
                              hipStream_t stream) {
    const float* x  = (const float*)d_in[0];
    const int*   ei = (const int*)d_in[1];
    const float* W1 = (const float*)d_in[2];
    const float* b1 = (const float*)d_in[3];
    const float* W2 = (const float*)d_in[4];
    const float* b2 = (const float*)d_in[5];
    const float* Wl = (const float*)d_in[6];
    const float* bl = (const float*)d_in[7];
    float* out = (float*)d_out;

    const int* src = ei;
    const int* dst = ei + N_EDGES;

    unsigned* hdr    = (unsigned*)d_ws;
    unsigned* cnt    = hdr;
    unsigned* base   = hdr + 8;
    unsigned* cursor = hdr + 16;
    float*    vc     = (float*)(hdr + 24);
    unsigned* pedge  = hdr + 64;
    float* partials  = (float*)(pedge + N_EDGES);
    float* dinv      = partials + NBUCK * ACC_SUB * BSIZE;
    float* xs        = dinv + N_NODES;
    float* us        = xs + N_NODES;
    float* uself     = us + N_NODES;

    hipMemsetAsync(d_ws, 0, 256, stream);   // zero bucketCnt (+hdr)

    const int node_blocks = (N_NODES + 255) / 256;
    const int p2_blocks   = (N_EDGES + P2_TILE - 1) / P2_TILE;

    p1_count<<<1024, 256, 0, stream>>>(dst, cnt);
    scan_prep<<<1, 64, 0, stream>>>(cnt, base, cursor, vc, W2, b2, Wl, bl);
    p2_partition<<<p2_blocks, P2_T, 0, stream>>>(src, dst, cursor, pedge);

    acc_kernel<<<NBUCK * ACC_SUB, ACC_T, 0, stream>>>(pedge, base, cnt, nullptr, partials);
    red_deg<<<node_blocks, 256, 0, stream>>>(partials, x, dinv, xs);

    acc_kernel<<<NBUCK * ACC_SUB, ACC_T, 0, stream>>>(pedge, base, cnt, xs, partials);
    red_s<<<node_blocks, 256, 0, stream>>>(partials, x, dinv, W1, b1, vc, us, uself);

    acc_kernel<<<NBUCK * ACC_SUB, ACC_T, 0, stream>>>(pedge, base, cnt, us, partials);
    red_r<<<node_blocks, 256, 0, stream>>>(partials, dinv, uself, vc, out);
}